// Round 9
// baseline (429.235 us; speedup 1.0000x reference)
//
#include <hip/hip_runtime.h>
#include <cstdint>
#include <cmath>

#define NB 8192
#define ND 128
#define NEG_INF (-__builtin_inff())

typedef __attribute__((ext_vector_type(8))) __bf16 bf16x8;
typedef __attribute__((ext_vector_type(2))) __bf16 bf16x2;
typedef __attribute__((ext_vector_type(4))) float f32x4;

// Insert v into ascending top-K list (identity when v <= t[0]).
__device__ __forceinline__ void insert10(float t[10], float v) {
#pragma unroll
  for (int j = 0; j < 9; ++j) t[j] = __builtin_amdgcn_fmed3f(t[j], t[j + 1], v);
  t[9] = fmaxf(t[9], v);
}
__device__ __forceinline__ void insert11(float t[11], float v) {
#pragma unroll
  for (int j = 0; j < 10; ++j) t[j] = __builtin_amdgcn_fmed3f(t[j], t[j + 1], v);
  t[10] = fmaxf(t[10], v);
}

// ---------------------------------------------------------------------------
// Row loss via column-10-only soft sort (P row-stochastic => p_neg = 1-p_pos,
// clips no-ops, both BCEs identical). Verified exact R3/R5-R8 (absmax 0).
// ---------------------------------------------------------------------------
__device__ float row_loss(float x[11]) {
  float al[55];
#pragma unroll
  for (int layer = 0; layer < 11; ++layer) {
#pragma unroll
    for (int p = 0; p < 5; ++p) {
      int ii = (layer & 1) + 2 * p;
      float av = x[ii], bv = x[ii + 1];
      float a = atanf(bv - av) * 0.3183098861837907f + 0.5f;
      al[layer * 5 + p] = a;
      float be = 1.f - a;
      x[ii] = a * av + be * bv;
      x[ii + 1] = be * av + a * bv;
    }
  }
  float v[11];
#pragma unroll
  for (int i = 0; i < 11; ++i) v[i] = 0.f;
  v[10] = 1.f;
#pragma unroll
  for (int layer = 10; layer >= 0; --layer) {
#pragma unroll
    for (int p = 0; p < 5; ++p) {
      int ii = (layer & 1) + 2 * p;
      float a = al[layer * 5 + p];
      float be = 1.f - a;
      float va = v[ii], vb = v[ii + 1];
      v[ii] = a * va + be * vb;
      v[ii + 1] = be * va + a * vb;
    }
  }
  float C = fmaxf(logf(v[10]), -100.f);
#pragma unroll
  for (int i = 0; i < 10; ++i) C += fmaxf(logf(1.f - v[i]), -100.f);
  return C;
}

// ---------------------------------------------------------------------------
// Kernel 1: row-normalize -> bf16 + fp32 pos_sims; block 0 zeroes d_out.
// ---------------------------------------------------------------------------
__global__ __launch_bounds__(256, 4) void knorm(const float* __restrict__ aug1,
                                                const float* __restrict__ aug2,
                                                __bf16* __restrict__ an,
                                                float* __restrict__ pos,
                                                float* __restrict__ out) {
  if (blockIdx.x == 0 && threadIdx.x == 0) out[0] = 0.f;
  int wid = threadIdx.x >> 6;
  int l = threadIdx.x & 63;
  int row = blockIdx.x * 4 + wid;
  const float2* a1 = (const float2*)(aug1) + (size_t)row * 64;
  const float2* a2 = (const float2*)(aug2) + (size_t)row * 64;
  float2 v1 = a1[l], v2 = a2[l];
  float ss1 = v1.x * v1.x + v1.y * v1.y;
  float ss2 = v2.x * v2.x + v2.y * v2.y;
  float dp = v1.x * v2.x + v1.y * v2.y;
#pragma unroll
  for (int off = 1; off < 64; off <<= 1) {
    ss1 += __shfl_xor(ss1, off);
    ss2 += __shfl_xor(ss2, off);
    dp += __shfl_xor(dp, off);
  }
  float inv1 = 1.0f / fmaxf(sqrtf(ss1), 1e-8f);
  float inv2 = 1.0f / fmaxf(sqrtf(ss2), 1e-8f);
  bf16x2 o1, o2;
  o1[0] = (__bf16)(v1.x * inv1);
  o1[1] = (__bf16)(v1.y * inv1);
  o2[0] = (__bf16)(v2.x * inv2);
  o2[1] = (__bf16)(v2.y * inv2);
  ((bf16x2*)(an))[(size_t)row * 64 + l] = o1;
  ((bf16x2*)(an + (size_t)NB * ND))[(size_t)row * 64 + l] = o2;
  if (l == 0) pos[row] = dp * inv1 * inv2;
}

// ---------------------------------------------------------------------------
// Kernel 2: fused Gram + BRANCHLESS per-(lane,rowblock) depth-4 sorted
// register chains (4 med3-class VALU per output value, unconditional -- no
// threshold, no stats, no branches, no atomics, no hot-loop LDS). Each chain
// sees 128 sims; a chain only drops values < its min, so the row is provably
// exact iff s10[0] >= max over chains of chain-min (checked in ksort; ~1%
// of rows fall back to the exact brute-force path).
// Diagonal: self-sim (~1.0, row max) enters a chain; the diag-containing
// quarter builds top-11 and drops the max in the epilogue.
// ---------------------------------------------------------------------------
__global__ __launch_bounds__(256, 3) void kgram(const __bf16* __restrict__ an_all,
                                                float* __restrict__ tk,
                                                float* __restrict__ qmg) {
  int dir = blockIdx.y;
  int rowg = blockIdx.x >> 2;
  int qtr = blockIdx.x & 3;
  const bf16x8* an8 = (const bf16x8*)(an_all + (size_t)dir * NB * ND);
  int w = threadIdx.x >> 6;
  int l = threadIdx.x & 63;
  int q = l >> 4;
  int c = l & 15;
  int row_base = rowg * 64;
  const int col0 = qtr * 2048;

  __shared__ float cand[64][65];  // [row][w*16+q*4+j], +1 pad: conflict-free

  // Row fragments (B-operand), resident all kernel (compiler -> AGPRs).
  bf16x8 brow[4][4];
#pragma unroll
  for (int rb = 0; rb < 4; ++rb)
#pragma unroll
    for (int kc = 0; kc < 4; ++kc)
      brow[rb][kc] = an8[(size_t)(row_base + rb * 16 + c) * 16 + kc * 4 + q];

  const bf16x8* pf0 = an8 + ((size_t)(col0 + w * 16 + c) * 16 + q);
  bf16x8 a[4], a2[4];
  const f32x4 zz = {0.f, 0.f, 0.f, 0.f};
  f32x4 acc[4];

  // Depth-4 ascending chains, one per row-block.
  float t4[4][4];
#pragma unroll
  for (int rb = 0; rb < 4; ++rb)
#pragma unroll
    for (int j = 0; j < 4; ++j) t4[rb][j] = NEG_INF;

  auto loadA = [&](int t) {
    const bf16x8* p = pf0 + (size_t)(t & 31) * 1024;
#pragma unroll
    for (int kc = 0; kc < 4; ++kc) a[kc] = p[kc * 4];
  };
  auto loadA2 = [&](int t) {
    const bf16x8* p = pf0 + (size_t)(t & 31) * 1024;
#pragma unroll
    for (int kc = 0; kc < 4; ++kc) a2[kc] = p[kc * 4];
  };
  auto mfma_tile = [&](const bf16x8* src) {
#pragma unroll
    for (int rb = 0; rb < 4; ++rb)
      acc[rb] = __builtin_amdgcn_mfma_f32_16x16x32_bf16(src[0], brow[rb][0], zz, 0, 0, 0);
#pragma unroll
    for (int kc = 1; kc < 4; ++kc)
#pragma unroll
      for (int rb = 0; rb < 4; ++rb)
        acc[rb] = __builtin_amdgcn_mfma_f32_16x16x32_bf16(src[kc], brow[rb][kc], acc[rb], 0, 0, 0);
  };
  auto consume = [&]() {  // 64 unconditional VALU ops, 4 independent chains
#pragma unroll
    for (int rb = 0; rb < 4; ++rb) {
#pragma unroll
      for (int r = 0; r < 4; ++r) {
        float v = acc[rb][r];
        t4[rb][0] = __builtin_amdgcn_fmed3f(t4[rb][0], t4[rb][1], v);
        t4[rb][1] = __builtin_amdgcn_fmed3f(t4[rb][1], t4[rb][2], v);
        t4[rb][2] = __builtin_amdgcn_fmed3f(t4[rb][2], t4[rb][3], v);
        t4[rb][3] = fmaxf(t4[rb][3], v);
      }
    }
  };

  loadA(0);
  loadA2(1);
  for (int t = 0; t < 32; t += 2) {
    mfma_tile(a);    // tile t
    loadA(t + 2);    // prefetch (wraps harmlessly at t=30)
    consume();       // tile t
    mfma_tile(a2);   // tile t+1
    loadA2(t + 3);   // prefetch (wraps harmlessly)
    consume();       // tile t+1
  }

  // ---- flush chains to LDS (deterministic slots, no atomics) ----
#pragma unroll
  for (int rb = 0; rb < 4; ++rb)
#pragma unroll
    for (int j = 0; j < 4; ++j)
      cand[rb * 16 + c][w * 16 + q * 4 + j] = t4[rb][j];
  __syncthreads();

  // ---- epilogue: per-row top-11 of 64 candidates + proof value ----
  if (threadIdx.x < 64) {
    int rl = threadIdx.x;
    float qm = NEG_INF;  // max over the 16 chains of chain-min (slot j=0)
#pragma unroll
    for (int s = 0; s < 16; ++s) qm = fmaxf(qm, cand[rl][s * 4]);
    float t11[11];
#pragma unroll
    for (int j = 0; j < 11; ++j) t11[j] = NEG_INF;
#pragma unroll 4
    for (int i = 0; i < 64; ++i) {
      float v = cand[rl][i];
      if (v > t11[0]) insert11(t11, v);
    }
    bool diagq = (row_base >= col0) && (row_base < col0 + 2048);
    float* o = tk + ((size_t)(dir * NB + row_base + rl) * 4 + qtr) * 10;
    if (diagq) {  // t11[10] is the self-sim (max) -> drop it
#pragma unroll
      for (int j = 0; j < 10; ++j) o[j] = t11[j];
    } else {
#pragma unroll
      for (int j = 0; j < 10; ++j) o[j] = t11[j + 1];
    }
    qmg[(dir * NB + row_base + rl) * 4 + qtr] = qm;
  }
}

// ---------------------------------------------------------------------------
// Kernel 3: merge 4 quarter-lists, chain-min proof, soft-sort + BCE; exact
// brute-force fallback (butterfly-merged) for unproven rows (~1%).
// ---------------------------------------------------------------------------
__global__ __launch_bounds__(64, 1) void ksort(const float* __restrict__ tk,
                                               const float* __restrict__ pos,
                                               const float* __restrict__ qmg,
                                               const __bf16* __restrict__ an_all,
                                               float* __restrict__ out) {
  int tid = blockIdx.x * 64 + threadIdx.x;
  int dir = tid >> 13;
  int row = tid & (NB - 1);
  int lane = threadIdx.x;

  const float* A = tk + (size_t)(dir * NB + row) * 40;
  float s10[10];
#pragma unroll
  for (int j = 0; j < 10; ++j) s10[j] = A[j];
#pragma unroll
  for (int g = 1; g < 4; ++g)
#pragma unroll
    for (int j = 0; j < 10; ++j) {
      float v = A[g * 10 + j];
      if (v > s10[0]) insert10(s10, v);
    }
  float4 qm = ((const float4*)qmg)[dir * NB + row];
  float qtmax = fmaxf(fmaxf(qm.x, qm.y), fmaxf(qm.z, qm.w));
  // Proof: any sim a chain dropped is < that chain's min <= qtmax <= s10[0]
  // -> not in the top-10 -> s10 is the exact top-10.
  bool ok = (s10[0] >= qtmax);

  float C = 0.f;
  if (ok) {
    float x[11];
#pragma unroll
    for (int j = 0; j < 10; ++j) x[j] = s10[j];
    x[10] = pos[row];
    C = row_loss(x);
  }
#pragma unroll
  for (int off = 1; off < 64; off <<= 1) C += __shfl_xor(C, off);
  if (lane == 0) atomicAdd(out, C * (-1.f / (2.f * (float)NB * 11.f)));

  // ---- exact fallback ----
  unsigned long long bad = __ballot(!ok);
  if (bad == 0ull) return;
  __shared__ float rv[128];
  const __bf16* an = an_all + (size_t)dir * NB * ND;
  while (bad) {
    int b = __ffsll((long long)bad) - 1;
    bad &= bad - 1;
    int brow = (blockIdx.x * 64 + b) & (NB - 1);
    bf16x2 pr = ((const bf16x2*)an)[(size_t)brow * 64 + lane];
    rv[lane * 2] = (float)pr[0];
    rv[lane * 2 + 1] = (float)pr[1];
    __syncthreads();
    float t10[10];
#pragma unroll
    for (int j = 0; j < 10; ++j) t10[j] = NEG_INF;
    for (int i = 0; i < 128; ++i) {
      int col = lane + i * 64;
      if (col == brow) continue;
      const bf16x8* cp = (const bf16x8*)(an + (size_t)col * ND);
      float d = 0.f;
#pragma unroll
      for (int k = 0; k < 16; ++k) {
        bf16x8 p = cp[k];
#pragma unroll
        for (int e = 0; e < 8; ++e) d = fmaf(rv[k * 8 + e], (float)p[e], d);
      }
      if (d > t10[0]) insert10(t10, d);
    }
    // Butterfly merge: all lanes converge to the global top-10.
#pragma unroll
    for (int off = 32; off >= 1; off >>= 1) {
#pragma unroll
      for (int j = 0; j < 10; ++j) {
        float v = __shfl_xor(t10[j], off);
        if (v > t10[0]) insert10(t10, v);
      }
    }
    if (lane == 0) {
      float x[11];
#pragma unroll
      for (int j = 0; j < 10; ++j) x[j] = t10[j];
      x[10] = pos[brow];
      atomicAdd(out, row_loss(x) * (-1.f / (2.f * (float)NB * 11.f)));
    }
    __syncthreads();
  }
}

// ---------------------------------------------------------------------------
// ws: [an bf16 4MB][pos 32KB][tk 2.62MB][qmg 256KB]. 3 nodes, no memsets.
// ---------------------------------------------------------------------------
extern "C" void kernel_launch(void* const* d_in, const int* in_sizes, int n_in,
                              void* d_out, int out_size, void* d_ws, size_t ws_size,
                              hipStream_t stream) {
  const float* aug1 = (const float*)d_in[0];
  const float* aug2 = (const float*)d_in[1];
  char* w = (char*)d_ws;
  __bf16* an = (__bf16*)w;
  float* pos = (float*)(w + (size_t)4 * 1024 * 1024);
  float* tk = pos + NB;
  float* qmg = tk + (size_t)2 * NB * 40;

  knorm<<<dim3(NB / 4), dim3(256), 0, stream>>>(aug1, aug2, an, pos, (float*)d_out);
  kgram<<<dim3(512, 2), dim3(256), 0, stream>>>(an, tk, qmg);
  ksort<<<dim3(2 * NB / 64), dim3(64), 0, stream>>>(tk, pos, qmg, an, (float*)d_out);
}

// Round 11
// 153.644 us; speedup vs baseline: 2.7937x; 2.7937x over previous
//
#include <hip/hip_runtime.h>
#include <cstdint>
#include <cmath>

#define NB 8192
#define ND 128
#define NEG_INF (-__builtin_inff())

typedef __attribute__((ext_vector_type(8))) __bf16 bf16x8;
typedef __attribute__((ext_vector_type(2))) __bf16 bf16x2;
typedef __attribute__((ext_vector_type(4))) float f32x4;

__device__ __forceinline__ void insert10(float t[10], float v) {
#pragma unroll
  for (int j = 0; j < 9; ++j) t[j] = __builtin_amdgcn_fmed3f(t[j], t[j + 1], v);
  t[9] = fmaxf(t[9], v);
}
__device__ __forceinline__ void insert11(float t[11], float v) {
#pragma unroll
  for (int j = 0; j < 10; ++j) t[j] = __builtin_amdgcn_fmed3f(t[j], t[j + 1], v);
  t[10] = fmaxf(t[10], v);
}

// Row loss via column-10-only soft sort (verified exact R3/R5-R9, absmax 0).
__device__ float row_loss(float x[11]) {
  float al[55];
#pragma unroll
  for (int layer = 0; layer < 11; ++layer) {
#pragma unroll
    for (int p = 0; p < 5; ++p) {
      int ii = (layer & 1) + 2 * p;
      float av = x[ii], bv = x[ii + 1];
      float a = atanf(bv - av) * 0.3183098861837907f + 0.5f;
      al[layer * 5 + p] = a;
      float be = 1.f - a;
      x[ii] = a * av + be * bv;
      x[ii + 1] = be * av + a * bv;
    }
  }
  float v[11];
#pragma unroll
  for (int i = 0; i < 11; ++i) v[i] = 0.f;
  v[10] = 1.f;
#pragma unroll
  for (int layer = 10; layer >= 0; --layer) {
#pragma unroll
    for (int p = 0; p < 5; ++p) {
      int ii = (layer & 1) + 2 * p;
      float a = al[layer * 5 + p];
      float be = 1.f - a;
      float va = v[ii], vb = v[ii + 1];
      v[ii] = a * va + be * vb;
      v[ii + 1] = be * va + a * vb;
    }
  }
  float C = fmaxf(logf(v[10]), -100.f);
#pragma unroll
  for (int i = 0; i < 10; ++i) C += fmaxf(logf(1.f - v[i]), -100.f);
  return C;
}

// ---------------------------------------------------------------------------
// Kernel 1: row-normalize -> bf16 + fp32 pos_sims; block 0 zeroes d_out.
// ---------------------------------------------------------------------------
__global__ __launch_bounds__(256, 4) void knorm(const float* __restrict__ aug1,
                                                const float* __restrict__ aug2,
                                                __bf16* __restrict__ an,
                                                float* __restrict__ pos,
                                                float* __restrict__ out) {
  if (blockIdx.x == 0 && threadIdx.x == 0) out[0] = 0.f;
  int wid = threadIdx.x >> 6;
  int l = threadIdx.x & 63;
  int row = blockIdx.x * 4 + wid;
  const float2* a1 = (const float2*)(aug1) + (size_t)row * 64;
  const float2* a2 = (const float2*)(aug2) + (size_t)row * 64;
  float2 v1 = a1[l], v2 = a2[l];
  float ss1 = v1.x * v1.x + v1.y * v1.y;
  float ss2 = v2.x * v2.x + v2.y * v2.y;
  float dp = v1.x * v2.x + v1.y * v2.y;
#pragma unroll
  for (int off = 1; off < 64; off <<= 1) {
    ss1 += __shfl_xor(ss1, off);
    ss2 += __shfl_xor(ss2, off);
    dp += __shfl_xor(dp, off);
  }
  float inv1 = 1.0f / fmaxf(sqrtf(ss1), 1e-8f);
  float inv2 = 1.0f / fmaxf(sqrtf(ss2), 1e-8f);
  bf16x2 o1, o2;
  o1[0] = (__bf16)(v1.x * inv1);
  o1[1] = (__bf16)(v1.y * inv1);
  o2[0] = (__bf16)(v2.x * inv2);
  o2[1] = (__bf16)(v2.y * inv2);
  ((bf16x2*)(an))[(size_t)row * 64 + l] = o1;
  ((bf16x2*)(an + (size_t)NB * ND))[(size_t)row * 64 + l] = o2;
  if (l == 0) pos[row] = dp * inv1 * inv2;
}

// ---------------------------------------------------------------------------
// Kernel 2: fused Gram + branchless depth-5 register chains.
// XCD-locality block decode: dir = bx&1, qtr = (bx>>1)&3, rowg = bx>>3.
// Under round-robin block->XCD dispatch each XCD sees ONE (dir,qtr):
// column stream = 512 KB -> L2-resident (prior layouts thrashed ~8 MB over
// the 4 MB per-XCD L2 -> L3-latency-bound, the R5-R9 ~80 µs plateau).
// Chains are unconditional (5 med3-class ops/value): no branches, atomics,
// or LDS in the hot loop. Proof in ksort: s10[0] >= max(chain mins);
// depth-5 -> P(fail) ~ 7e-6/row.
// ---------------------------------------------------------------------------
__global__ __launch_bounds__(256, 3) void kgram(const __bf16* __restrict__ an_all,
                                                float* __restrict__ tk,
                                                float* __restrict__ qmg) {
  int bx = blockIdx.x;
  int dir = bx & 1;
  int qtr = (bx >> 1) & 3;
  int rowg = bx >> 3;
  const bf16x8* an8 = (const bf16x8*)(an_all + (size_t)dir * NB * ND);
  int w = threadIdx.x >> 6;
  int l = threadIdx.x & 63;
  int q = l >> 4;
  int c = l & 15;
  int row_base = rowg * 64;
  const int col0 = qtr * 2048;

  __shared__ float cand[64][81];  // 16 chains x 5 per row, +1 pad

  bf16x8 brow[4][4];
#pragma unroll
  for (int rb = 0; rb < 4; ++rb)
#pragma unroll
    for (int kc = 0; kc < 4; ++kc)
      brow[rb][kc] = an8[(size_t)(row_base + rb * 16 + c) * 16 + kc * 4 + q];

  const bf16x8* pf0 = an8 + ((size_t)(col0 + w * 16 + c) * 16 + q);
  bf16x8 a[4], a2[4];
  const f32x4 zz = {0.f, 0.f, 0.f, 0.f};
  f32x4 acc[4];

  float t5[4][5];
#pragma unroll
  for (int rb = 0; rb < 4; ++rb)
#pragma unroll
    for (int j = 0; j < 5; ++j) t5[rb][j] = NEG_INF;

  auto loadA = [&](int t) {
    const bf16x8* p = pf0 + (size_t)(t & 31) * 1024;
#pragma unroll
    for (int kc = 0; kc < 4; ++kc) a[kc] = p[kc * 4];
  };
  auto loadA2 = [&](int t) {
    const bf16x8* p = pf0 + (size_t)(t & 31) * 1024;
#pragma unroll
    for (int kc = 0; kc < 4; ++kc) a2[kc] = p[kc * 4];
  };
  auto mfma_tile = [&](const bf16x8* src) {
#pragma unroll
    for (int rb = 0; rb < 4; ++rb)
      acc[rb] = __builtin_amdgcn_mfma_f32_16x16x32_bf16(src[0], brow[rb][0], zz, 0, 0, 0);
#pragma unroll
    for (int kc = 1; kc < 4; ++kc)
#pragma unroll
      for (int rb = 0; rb < 4; ++rb)
        acc[rb] = __builtin_amdgcn_mfma_f32_16x16x32_bf16(src[kc], brow[rb][kc], acc[rb], 0, 0, 0);
  };
  auto consume = [&]() {
#pragma unroll
    for (int rb = 0; rb < 4; ++rb) {
#pragma unroll
      for (int r = 0; r < 4; ++r) {
        float v = acc[rb][r];
        t5[rb][0] = __builtin_amdgcn_fmed3f(t5[rb][0], t5[rb][1], v);
        t5[rb][1] = __builtin_amdgcn_fmed3f(t5[rb][1], t5[rb][2], v);
        t5[rb][2] = __builtin_amdgcn_fmed3f(t5[rb][2], t5[rb][3], v);
        t5[rb][3] = __builtin_amdgcn_fmed3f(t5[rb][3], t5[rb][4], v);
        t5[rb][4] = fmaxf(t5[rb][4], v);
      }
    }
  };

  loadA(0);
  loadA2(1);
  for (int t = 0; t < 32; t += 2) {
    mfma_tile(a);
    loadA(t + 2);    // wraps harmlessly at the end
    consume();
    mfma_tile(a2);
    loadA2(t + 3);
    consume();
  }

  // flush chains: row rl = rb*16+c, chain slot = w*20 + q*5 + j
#pragma unroll
  for (int rb = 0; rb < 4; ++rb)
#pragma unroll
    for (int j = 0; j < 5; ++j)
      cand[rb * 16 + c][w * 20 + q * 5 + j] = t5[rb][j];
  __syncthreads();

  if (threadIdx.x < 64) {
    int rl = threadIdx.x;
    float qm = NEG_INF;  // max over 16 chains of chain-min (slot j=0)
#pragma unroll
    for (int s = 0; s < 16; ++s) qm = fmaxf(qm, cand[rl][s * 5]);
    float t11[11];
#pragma unroll
    for (int j = 0; j < 11; ++j) t11[j] = NEG_INF;
#pragma unroll 4
    for (int i = 0; i < 80; ++i) {
      float v = cand[rl][i];
      if (v > t11[0]) insert11(t11, v);
    }
    bool diagq = (row_base >= col0) && (row_base < col0 + 2048);
    float* o = tk + ((size_t)(dir * NB + row_base + rl) * 4 + qtr) * 10;
    if (diagq) {  // t11[10] is the self-sim (max) -> drop it
#pragma unroll
      for (int j = 0; j < 10; ++j) o[j] = t11[j];
    } else {
#pragma unroll
      for (int j = 0; j < 10; ++j) o[j] = t11[j + 1];
    }
    qmg[(dir * NB + row_base + rl) * 4 + qtr] = qm;
  }
}

// ---------------------------------------------------------------------------
// Kernel 3: merge 4 quarter-lists, chain-min proof, soft-sort + BCE; exact
// ILP fallback (4 accumulators + butterfly merge) for unproven rows.
// Block = 64 threads = 1 wave; dir uniform per block.
// ---------------------------------------------------------------------------
__global__ __launch_bounds__(64, 1) void ksort(const float* __restrict__ tk,
                                               const float* __restrict__ pos,
                                               const float* __restrict__ qmg,
                                               const __bf16* __restrict__ an_all,
                                               float* __restrict__ out) {
  int tid = blockIdx.x * 64 + threadIdx.x;
  int dir = tid >> 13;
  int row = tid & (NB - 1);
  int lane = threadIdx.x;

  const float* A = tk + (size_t)(dir * NB + row) * 40;
  float s10[10];
#pragma unroll
  for (int j = 0; j < 10; ++j) s10[j] = A[j];
#pragma unroll
  for (int g = 1; g < 4; ++g)
#pragma unroll
    for (int j = 0; j < 10; ++j) {
      float v = A[g * 10 + j];
      if (v > s10[0]) insert10(s10, v);
    }
  float4 qm = ((const float4*)qmg)[dir * NB + row];
  float qtmax = fmaxf(fmaxf(qm.x, qm.y), fmaxf(qm.z, qm.w));
  bool ok = (s10[0] >= qtmax);  // depth-5: P(!ok) ~ 7e-6 per row

  float C = 0.f;
  if (ok) {
    float x[11];
#pragma unroll
    for (int j = 0; j < 10; ++j) x[j] = s10[j];
    x[10] = pos[row];
    C = row_loss(x);
  }
#pragma unroll
  for (int off = 1; off < 64; off <<= 1) C += __shfl_xor(C, off);
  if (lane == 0) atomicAdd(out, C * (-1.f / (2.f * (float)NB * 11.f)));

  // ---- exact fallback (expected ~0.1 rows device-wide) ----
  unsigned long long bad = __ballot(!ok);
  if (bad == 0ull) return;
  __shared__ float rv[128];
  const __bf16* an = an_all + (size_t)dir * NB * ND;
  while (bad) {
    int b = __ffsll((long long)bad) - 1;
    bad &= bad - 1;
    int brow = (blockIdx.x * 64 + b) & (NB - 1);
    bf16x2 pr = ((const bf16x2*)an)[(size_t)brow * 64 + lane];
    rv[lane * 2] = (float)pr[0];
    rv[lane * 2 + 1] = (float)pr[1];
    __syncthreads();
    float t10[10];
#pragma unroll
    for (int j = 0; j < 10; ++j) t10[j] = NEG_INF;
    for (int i = 0; i < 128; ++i) {
      int col = lane + i * 64;
      const bf16x8* cp = (const bf16x8*)(an + (size_t)col * ND);
      float d0 = 0.f, d1 = 0.f, d2 = 0.f, d3 = 0.f;  // 4-way ILP
#pragma unroll
      for (int k = 0; k < 16; ++k) {
        bf16x8 p = cp[k];
        d0 = fmaf(rv[k * 8 + 0], (float)p[0], d0);
        d1 = fmaf(rv[k * 8 + 1], (float)p[1], d1);
        d2 = fmaf(rv[k * 8 + 2], (float)p[2], d2);
        d3 = fmaf(rv[k * 8 + 3], (float)p[3], d3);
        d0 = fmaf(rv[k * 8 + 4], (float)p[4], d0);
        d1 = fmaf(rv[k * 8 + 5], (float)p[5], d1);
        d2 = fmaf(rv[k * 8 + 6], (float)p[6], d2);
        d3 = fmaf(rv[k * 8 + 7], (float)p[7], d3);
      }
      float d = (d0 + d1) + (d2 + d3);
      d = (col == brow) ? NEG_INF : d;
      if (d > t10[0]) insert10(t10, d);
    }
#pragma unroll
    for (int off = 32; off >= 1; off >>= 1) {
#pragma unroll
      for (int j = 0; j < 10; ++j) {
        float v = __shfl_xor(t10[j], off);
        if (v > t10[0]) insert10(t10, v);
      }
    }
    if (lane == 0) {
      float x[11];
#pragma unroll
      for (int j = 0; j < 10; ++j) x[j] = t10[j];
      x[10] = pos[brow];
      atomicAdd(out, row_loss(x) * (-1.f / (2.f * (float)NB * 11.f)));
    }
    __syncthreads();
  }
}

// ---------------------------------------------------------------------------
// ws: [an bf16 4MB][pos 32KB][tk 2.62MB][qmg 256KB]. 3 nodes, no memsets.
// ---------------------------------------------------------------------------
extern "C" void kernel_launch(void* const* d_in, const int* in_sizes, int n_in,
                              void* d_out, int out_size, void* d_ws, size_t ws_size,
                              hipStream_t stream) {
  const float* aug1 = (const float*)d_in[0];
  const float* aug2 = (const float*)d_in[1];
  char* w = (char*)d_ws;
  __bf16* an = (__bf16*)w;
  float* pos = (float*)(w + (size_t)4 * 1024 * 1024);
  float* tk = pos + NB;
  float* qmg = tk + (size_t)2 * NB * 40;

  knorm<<<dim3(NB / 4), dim3(256), 0, stream>>>(aug1, aug2, an, pos, (float*)d_out);
  kgram<<<dim3(1024), dim3(256), 0, stream>>>(an, tk, qmg);
  ksort<<<dim3(2 * NB / 64), dim3(64), 0, stream>>>(tk, pos, qmg, an, (float*)d_out);
}